// Round 4
// baseline (4705.408 us; speedup 1.0000x reference)
//
#include <hip/hip_runtime.h>
#include <hip/hip_bf16.h>
#include <stdint.h>

// RecognitionODEGRU R10 — 2 chains per block, interleaved sub-phases.
// R9 lesson: chain-on-one-XCD kills weight L2 residency (7MB set > 4MB L2);
// staging win < weight loss. R10 reverts to R7's proven layout + MALL
// handshake VERBATIM, and instead HIDES handshake latency: 128 blocks, block
// (mp,nb) runs chains 2mp/2mp+1; each phase interleaves A then B, so the
// publish->wait dead time of one chain is covered by the other chain's
// stage+compute. Two 66KB slabs in LDS; W3 now streamed from L2 (slice is
// XCD-L2-resident with 16-chain reuse, like W2). Weight frags get L1 reuse
// on the B pass. Counters/targets/protocol identical to R7.
//
// Shapes: B=512, T=8, D=512, H=512, NSTEPS=4.
// d_out: outs[-1] (512,128) | h (512,512) | c=zeros (512,512), f32.

#define B_ 512
#define T_ 8
#define H_ 512
#define D_ 512

typedef short short8 __attribute__((ext_vector_type(8)));
typedef float f32x4 __attribute__((ext_vector_type(4)));
typedef __hip_bfloat16 bf16;
typedef unsigned long long u64;

__device__ __forceinline__ float sigm(float x){ return 1.f/(1.f+__expf(-x)); }

#define MFMA16(a,b,c) __builtin_amdgcn_mfma_f32_16x16x32_bf16((a),(b),(c),0,0,0)
#define ALD4(p)   __hip_atomic_load((p), __ATOMIC_RELAXED, __HIP_MEMORY_SCOPE_AGENT)
#define AST8(p,v) __hip_atomic_store((u64*)(p),(v),__ATOMIC_RELAXED,__HIP_MEMORY_SCOPE_AGENT)

__device__ __forceinline__ void wait_ge(unsigned* c, unsigned tgt, int* dead){
  if (threadIdx.x == 0){
    if (!*dead){
      int it = 0;
      while (ALD4(c) < tgt){
        __builtin_amdgcn_s_sleep(1);
        if (++it > 50000000){ *dead = 1; break; }  // terminate visibly, no hang
      }
    }
  }
  __syncthreads();
}
__device__ __forceinline__ void publish(unsigned* c){
  __builtin_amdgcn_s_waitcnt(0);   // each wave drains its stores before barrier
  __syncthreads();
  if (threadIdx.x == 0)
    __hip_atomic_fetch_add(c, 1u, __ATOMIC_RELAXED, __HIP_MEMORY_SCOPE_AGENT);
}

// Coherent slab stage: CH 16B-chunks/thread, 2^SH chunks per row (MALL path).
template<int CH, int SH>
__device__ __forceinline__ void stageC16(bf16* lds, int lstr, const bf16* g, int gstr){
  f32x4 tmp[CH];
#pragma unroll
  for (int j = 0; j < CH; ++j){
    int idx = j*256 + threadIdx.x;
    const bf16* p = g + (size_t)(idx >> SH)*gstr + (size_t)(idx & ((1<<SH)-1))*8;
    asm volatile("global_load_dwordx4 %0, %1, off sc0 sc1" : "=v"(tmp[j]) : "v"(p));
  }
  asm volatile("s_waitcnt vmcnt(0)" ::: "memory");
  __builtin_amdgcn_sched_barrier(0);   // keep ds_writes below the waitcnt
#pragma unroll
  for (int j = 0; j < CH; ++j){
    int idx = j*256 + threadIdx.x;
    *(f32x4*)&lds[(idx >> SH)*lstr + (idx & ((1<<SH)-1))*8] = tmp[j];
  }
}
// Plain (L2-cached) slab stage: CH 16B-chunks/thread, 2^SH chunks per row.
template<int CH, int SH>
__device__ __forceinline__ void stageP(bf16* lds, int lstr, const bf16* g, size_t gstr){
#pragma unroll
  for (int j = 0; j < CH; ++j){
    int idx = j*256 + threadIdx.x;
    *(short8*)&lds[(idx >> SH)*lstr + (idx & ((1<<SH)-1))*8] =
        *(const short8*)(g + (size_t)(idx >> SH)*gstr + (size_t)(idx & ((1<<SH)-1))*8);
  }
}

__device__ __forceinline__ u64 pk4(float a0, float a1, float a2, float a3){
  union { bf16 h[4]; u64 q; } u;
  u.h[0] = __float2bfloat16(a0); u.h[1] = __float2bfloat16(a1);
  u.h[2] = __float2bfloat16(a2); u.h[3] = __float2bfloat16(a3);
  return u.q;
}

// LDS: slabA 32x1032 @0 (66048B) | slabB 32x1032 @66048 (66048B)
//      t-arrays [2 chains][t0s|dts|tcs][32] @132096 (768B) | dead @132864
__global__ __launch_bounds__(256, 1) void persist_k(
    const bf16* __restrict__ W1hb, const bf16* __restrict__ W2b,
    const bf16* __restrict__ W3b,  const bf16* __restrict__ Woutb,
    const bf16* __restrict__ Wc3,  const bf16* __restrict__ xbf,
    const float* __restrict__ b1,  const float* __restrict__ b2,
    const float* __restrict__ b3,  const float* __restrict__ bout,
    const float* __restrict__ bcb3,const float* __restrict__ w1t,
    const float* __restrict__ ts,
    bf16* wbuf, bf16* z1buf, bf16* z2buf,
    unsigned* cnts, float* dout)
{
  extern __shared__ char smem[];
  bf16* slabA[2] = {(bf16*)smem, (bf16*)(smem + 66048)};
  float* t0sA[2], *dtsA[2], *tcsA[2];
  t0sA[0] = (float*)(smem + 132096); dtsA[0] = t0sA[0] + 32; tcsA[0] = t0sA[0] + 64;
  t0sA[1] = t0sA[0] + 96;            dtsA[1] = t0sA[0] + 128; tcsA[1] = t0sA[0] + 160;
  int* dead = (int*)(smem + 132864);

  const int tid = threadIdx.x, lane = tid & 63, wv = tid >> 6;
  const int fr = lane & 15, quad = lane >> 4;
  const int nb = blockIdx.x & 15;     // weight slice — XCD = nb%8 (L2 residency)
  const int mp = blockIdx.x >> 4;     // 8 chain-pairs
  const int gm0c[2] = {(2*mp)*32, (2*mp + 1)*32};
  unsigned* cb[2] = {cnts + (2*mp)*128, cnts + (2*mp + 1)*128};
  const int wm = wv & 1;              // batch half (k/gates/final-h)
  const int wn = wv >> 1;             // 16-col half (k/gates/final-h)

  if (tid < 32){
#pragma unroll
    for (int c = 0; c < 2; ++c){
      float t0 = ts[(gm0c[c] + tid)*T_];
      t0sA[c][tid] = t0; tcsA[c][tid] = t0; dtsA[c][tid] = 0.f;
    }
  }
  if (tid == 0) *dead = 0;
  __syncthreads();

  // per-lane constant vectors (4 consecutive output cols: quad*4 + j)
  const int zc0 = 64*nb + 16*wv + quad*4;   // z-phase col base (per-wave N-slice)
  const int kc0 = 32*nb + 16*wn + quad*4;   // k/gates/final-h col base
  const f32x4 b1v  = *(const f32x4*)&b1[zc0];
  const f32x4 w1tv = *(const f32x4*)&w1t[zc0];
  const f32x4 b2v  = *(const f32x4*)&b2[zc0];
  const f32x4 b3v  = *(const f32x4*)&b3[kc0];
  f32x4 bcv[4];
#pragma unroll
  for (int g = 0; g < 4; ++g)
    bcv[g] = *(const f32x4*)&bcb3[nb*128 + g*32 + 16*wn + quad*4];
  const f32x4 bov = *(const f32x4*)&bout[16*(nb & 7) + quad*4];

  // weight row pointers (shared by both chains — L1 reuse on the B pass)
  const bf16* w1p = W1hb  + (size_t)(64*nb + 16*wv + fr)*512  + quad*8;
  const bf16* w2p = W2b   + (size_t)(64*nb + 16*wv + fr)*1024 + quad*8;
  const bf16* w3p = W3b   + (size_t)(32*nb + 16*wn + fr)*1024 + quad*8;
  const bf16* wop = Woutb + (size_t)(16*(nb & 7) + fr)*512 + quad*8;
  const bf16* wcp[4];
#pragma unroll
  for (int g = 0; g < 4; ++g)
    wcp[g] = Wc3 + (size_t)(nb*128 + g*32 + 16*wn + fr)*1024 + quad*8;

  float hreg[2][4] = {{0,0,0,0},{0,0,0,0}}, kacc[2][4] = {{0,0,0,0},{0,0,0,0}};
  unsigned tz1[2] = {16,16}, tz2[2] = {16,16}, tw[2] = {16,16}, tg[2] = {16,16};

  for (int s = 0; s < T_; ++s){
    for (int sub = 0; sub < 4; ++sub){
      for (int e = 1; e <= 4; ++e){
        // ===== z1 = swish(w @ W1^T + t*w1t + b1), M32 N64 K512 — A then B ====
#pragma unroll
        for (int c = 0; c < 2; ++c){
          bf16* slab = slabA[c];
          wait_ge(cb[c] + 64, tw[c], dead);
          stageC16<8,6>(slab, 520, wbuf + (size_t)gm0c[c]*512, 512);
          __syncthreads();
          f32x4 a0 = {0,0,0,0}, a1 = {0,0,0,0};
#pragma unroll 4
          for (int k = 0; k < 16; ++k){
            short8 wt = *(const short8*)(w1p + k*32);
            a0 = MFMA16(wt, *(const short8*)&slab[fr*520      + k*32 + quad*8], a0);
            a1 = MFMA16(wt, *(const short8*)&slab[(16+fr)*520 + k*32 + quad*8], a1);
          }
          float t0v = tcsA[c][fr], t1v = tcsA[c][16 + fr];
          float s0[4], s1[4];
#pragma unroll
          for (int j = 0; j < 4; ++j){
            float v0 = a0[j] + b1v[j] + t0v*w1tv[j];
            float v1 = a1[j] + b1v[j] + t1v*w1tv[j];
            s0[j] = v0*sigm(v0); s1[j] = v1*sigm(v1);
          }
          AST8(z1buf + (size_t)(gm0c[c] + fr)*1024 + zc0,      pk4(s0[0],s0[1],s0[2],s0[3]));
          AST8(z1buf + (size_t)(gm0c[c] + 16 + fr)*1024 + zc0, pk4(s1[0],s1[1],s1[2],s1[3]));
          publish(cb[c] + 0);
        }
        // ===== z2 = swish(z1 @ W2^T + b2), M32 N64 K1024 — A then B =========
#pragma unroll
        for (int c = 0; c < 2; ++c){
          bf16* slab = slabA[c];
          wait_ge(cb[c] + 0, tz1[c], dead); tz1[c] += 16;
          stageC16<16,7>(slab, 1032, z1buf + (size_t)gm0c[c]*1024, 1024);
          __syncthreads();
          f32x4 a0 = {0,0,0,0}, a1 = {0,0,0,0};
#pragma unroll 4
          for (int k = 0; k < 32; ++k){
            short8 wt = *(const short8*)(w2p + k*32);
            a0 = MFMA16(wt, *(const short8*)&slab[fr*1032      + k*32 + quad*8], a0);
            a1 = MFMA16(wt, *(const short8*)&slab[(16+fr)*1032 + k*32 + quad*8], a1);
          }
          float s0[4], s1[4];
#pragma unroll
          for (int j = 0; j < 4; ++j){
            float v0 = a0[j] + b2v[j], v1 = a1[j] + b2v[j];
            s0[j] = v0*sigm(v0); s1[j] = v1*sigm(v1);
          }
          AST8(z2buf + (size_t)(gm0c[c] + fr)*1024 + zc0,      pk4(s0[0],s0[1],s0[2],s0[3]));
          AST8(z2buf + (size_t)(gm0c[c] + 16 + fr)*1024 + zc0, pk4(s1[0],s1[1],s1[2],s1[3]));
          publish(cb[c] + 32);
        }
        // ===== k = z2 @ W3^T + b3 ; RK4 in registers — A then B =============
#pragma unroll
        for (int c = 0; c < 2; ++c){
          bf16* slab = slabA[c];
          wait_ge(cb[c] + 32, tz2[c], dead); tz2[c] += 16;
          stageC16<16,7>(slab, 1032, z2buf + (size_t)gm0c[c]*1024, 1024);
          __syncthreads();
          f32x4 ak = {0,0,0,0};
#pragma unroll 8
          for (int k = 0; k < 32; ++k){
            ak = MFMA16(*(const short8*)(w3p + k*32),
                        *(const short8*)&slab[(wm*16 + fr)*1032 + k*32 + quad*8], ak);
          }
          const int r = wm*16 + fr;
          const float dtv = dtsA[c][r];
          float w4[4];
#pragma unroll
          for (int j = 0; j < 4; ++j){
            float v = ak[j] + b3v[j];
            float ka = (e == 1) ? v : kacc[c][j] + ((e == 4) ? 1.f : 2.f)*v;
            if (e < 4){ kacc[c][j] = ka; w4[j] = hreg[c][j] + ((e == 3) ? 1.f : 0.5f)*dtv*v; }
            else      { hreg[c][j] = hreg[c][j] + dtv*(1.f/6.f)*ka; w4[j] = hreg[c][j]; }
          }
          AST8(wbuf + (size_t)(gm0c[c] + r)*512 + kc0, pk4(w4[0],w4[1],w4[2],w4[3]));
          if (tid < 32){
            float ce = (e <= 2) ? ((float)sub + 0.5f) : ((float)sub + 1.f);
            tcsA[c][tid] = t0sA[c][tid] + dtsA[c][tid]*ce;
          }
          publish(cb[c] + 64); tw[c] += 16;
        }
      }
    }
    // ===== gates: [w|x_s] @ Wc3^T (4 groups r|z|hn|in x 32 cols) — A, B =====
#pragma unroll
    for (int c = 0; c < 2; ++c){
      bf16* slab = slabA[c];
      wait_ge(cb[c] + 64, tw[c], dead);
      stageC16<8,6>(slab, 1032, wbuf + (size_t)gm0c[c]*512, 512);
      stageP<8,6>(slab + 512, 1032, xbf + ((size_t)gm0c[c]*T_ + s)*512, (size_t)T_*512);
      __syncthreads();
      publish(cb[c] + 96);  // old w consumed (staged); safe to overwrite after all 16
      f32x4 ag[4] = {{0,0,0,0},{0,0,0,0},{0,0,0,0},{0,0,0,0}};
#pragma unroll 4
      for (int k = 0; k < 32; ++k){
        short8 xv = *(const short8*)&slab[(wm*16 + fr)*1032 + k*32 + quad*8];
#pragma unroll
        for (int g = 0; g < 4; ++g)
          ag[g] = MFMA16(*(const short8*)(wcp[g] + k*32), xv, ag[g]);
      }
      wait_ge(cb[c] + 96, tg[c], dead); tg[c] += 16;
      const int r = wm*16 + fr;
#pragma unroll
      for (int j = 0; j < 4; ++j){
        float r_ = sigm(ag[0][j] + bcv[0][j]);
        float z_ = sigm(ag[1][j] + bcv[1][j]);
        float hn = ag[2][j] + bcv[2][j];
        float in = ag[3][j] + bcv[3][j];
        float n_ = tanhf(in + r_*hn);
        hreg[c][j] = (1.f - z_)*n_ + z_*hreg[c][j];
      }
      AST8(wbuf + (size_t)(gm0c[c] + r)*512 + kc0, pk4(hreg[c][0],hreg[c][1],hreg[c][2],hreg[c][3]));
      if (tid < 32){
        float t0n = ts[(gm0c[c] + tid)*T_ + s];
        float t1  = (s < T_-1) ? ts[(gm0c[c] + tid)*T_ + s + 1] : t0n;
        t0sA[c][tid] = t0n; tcsA[c][tid] = t0n; dtsA[c][tid] = (t1 - t0n)*0.25f;
      }
      publish(cb[c] + 64); tw[c] += 16;
    }
  }
  // ===== final: out = h @ Wout^T + bout ; h ; c = 0 — per chain =============
#pragma unroll
  for (int c = 0; c < 2; ++c){
    bf16* slab = slabA[c];
    wait_ge(cb[c] + 64, tw[c], dead);
    stageC16<8,6>(slab, 520, wbuf + (size_t)gm0c[c]*512, 512);
    __syncthreads();
    if (nb < 8 && wv < 2){   // 8 n-blocks x 16 cols cover the 128 outs; wv = batch half
      f32x4 ao = {0,0,0,0};
#pragma unroll 4
      for (int k = 0; k < 16; ++k){
        ao = MFMA16(*(const short8*)(wop + k*32),
                    *(const short8*)&slab[(wv*16 + fr)*520 + k*32 + quad*8], ao);
      }
      f32x4 o;
#pragma unroll
      for (int j = 0; j < 4; ++j) o[j] = ao[j] + bov[j];
      *(f32x4*)&dout[(size_t)(gm0c[c] + wv*16 + fr)*128 + 16*nb + quad*4] = o;
    }
    {
      const int r = wm*16 + fr;
      f32x4 hv; hv[0]=hreg[c][0]; hv[1]=hreg[c][1]; hv[2]=hreg[c][2]; hv[3]=hreg[c][3];
      *(f32x4*)&dout[(size_t)B_*128 + (size_t)(gm0c[c] + r)*512 + kc0] = hv;
      f32x4 z4 = {0,0,0,0};
      *(f32x4*)&dout[(size_t)B_*128 + (size_t)B_*512 + (size_t)(gm0c[c] + r)*512 + kc0] = z4;
    }
  }
}

// ---- prolog kernels ----
__global__ void conv_k(const float* __restrict__ in, bf16* __restrict__ out,
                       int rows, int kin, int kout)
{
  int idx = blockIdx.x*256 + threadIdx.x;
  if (idx >= rows*kout) return;
  int r = idx / kout, k = idx - r*kout;
  out[idx] = __float2bfloat16(k < kin ? in[(size_t)r*kin + k] : 0.f);
}

__global__ void w1t_k(const float* __restrict__ W1, float* __restrict__ w1t)
{
  int i = blockIdx.x*256 + threadIdx.x;
  if (i < 1024) w1t[i] = W1[(size_t)i*513 + 512];
}

// Wc3 row R = n16*128 + g*32 + c; hidden col hc = n16*32 + c.
// K: [0:512]=h-part, [512:1024]=x-part. g=0:r g=1:z g=2:hn=[Whh_n|0] g=3:in=[0|Wih_n].
__global__ void wc3_k(const float* __restrict__ Wih, const float* __restrict__ Whh,
                      const float* __restrict__ bih, const float* __restrict__ bhh,
                      bf16* __restrict__ Wc3, float* __restrict__ bcb3)
{
  int idx = blockIdx.x*256 + threadIdx.x;
  if (idx >= 2048*1024) return;
  int R = idx >> 10, k = idx & 1023;
  int n16 = R >> 7, g = (R >> 5) & 3, c = R & 31;
  int hc = n16*32 + c;
  float v;
  if      (g == 0) v = (k < 512) ? Whh[(size_t)hc*512 + k]        : Wih[(size_t)hc*512 + k - 512];
  else if (g == 1) v = (k < 512) ? Whh[(size_t)(512+hc)*512 + k]  : Wih[(size_t)(512+hc)*512 + k - 512];
  else if (g == 2) v = (k < 512) ? Whh[(size_t)(1024+hc)*512 + k] : 0.f;
  else             v = (k < 512) ? 0.f                             : Wih[(size_t)(1024+hc)*512 + k - 512];
  Wc3[idx] = __float2bfloat16(v);
  if (k == 0){
    if      (g == 0) bcb3[R] = bih[hc] + bhh[hc];
    else if (g == 1) bcb3[R] = bih[512 + hc] + bhh[512 + hc];
    else if (g == 2) bcb3[R] = bhh[1024 + hc];
    else             bcb3[R] = bih[1024 + hc];
  }
}

__global__ void init_k(bf16* __restrict__ wbuf, unsigned* __restrict__ cnts)
{
  int idx = blockIdx.x*256 + threadIdx.x;
  if (idx < B_*H_) wbuf[idx] = __float2bfloat16(0.f);
  if (idx < 16*128){
    int off = idx & 127;
    cnts[idx] = (off == 64) ? 16u : 0u;   // cw pre-armed (initial w=0 published)
  }
}

extern "C" void kernel_launch(void* const* d_in, const int* in_sizes, int n_in,
                              void* d_out, int out_size, void* d_ws, size_t ws_size,
                              hipStream_t stream)
{
  const float* x    = (const float*)d_in[0];
  const float* ts   = (const float*)d_in[1];
  const float* Wih  = (const float*)d_in[2];
  const float* Whh  = (const float*)d_in[3];
  const float* bih  = (const float*)d_in[4];
  const float* bhh  = (const float*)d_in[5];
  const float* Wout = (const float*)d_in[6];
  const float* bout = (const float*)d_in[7];
  const float* W1   = (const float*)d_in[8];
  const float* b1   = (const float*)d_in[9];
  const float* W2   = (const float*)d_in[10];
  const float* b2   = (const float*)d_in[11];
  const float* W3   = (const float*)d_in[12];
  const float* b3   = (const float*)d_in[13];

  char* ws = (char*)d_ws;
  size_t off = 0;
  auto alloc = [&](size_t n){ void* p = ws + off; off += (n + 255) & ~(size_t)255; return p; };

  bf16* xbf   = (bf16*)alloc((size_t)B_*T_*D_*2);
  bf16* W1hb  = (bf16*)alloc((size_t)1024*512*2);
  bf16* W2b   = (bf16*)alloc((size_t)1024*1024*2);
  bf16* W3b   = (bf16*)alloc((size_t)512*1024*2);
  bf16* Woutb = (bf16*)alloc((size_t)128*512*2);
  bf16* Wc3   = (bf16*)alloc((size_t)2048*1024*2);
  float* bcb3 = (float*)alloc((size_t)2048*4);
  float* w1t  = (float*)alloc((size_t)1024*4);
  bf16* wbuf  = (bf16*)alloc((size_t)B_*H_*2);
  bf16* z1buf = (bf16*)alloc((size_t)B_*1024*2);
  bf16* z2buf = (bf16*)alloc((size_t)B_*1024*2);
  unsigned* cnts = (unsigned*)alloc((size_t)16*128*4);

  auto conv = [&](const float* in, bf16* out, int rows, int kin, int kout){
    int n = rows*kout;
    conv_k<<<(n + 255)/256, 256, 0, stream>>>(in, out, rows, kin, kout);
  };
  conv(x, xbf, B_*T_, D_, D_);
  conv(W1, W1hb, 1024, 513, 512);   // col 512 handled via w1t rank-1 term
  conv(W2, W2b, 1024, 1024, 1024);
  conv(W3, W3b, 512, 1024, 1024);
  conv(Wout, Woutb, 128, 512, 512);
  w1t_k<<<4, 256, 0, stream>>>(W1, w1t);
  wc3_k<<<(2048*1024)/256, 256, 0, stream>>>(Wih, Whh, bih, bhh, Wc3, bcb3);
  init_k<<<(B_*H_ + 255)/256, 256, 0, stream>>>(wbuf, cnts);

  (void)hipFuncSetAttribute((const void*)persist_k,
                            hipFuncAttributeMaxDynamicSharedMemorySize, 133120);
  persist_k<<<128, 256, 133120, stream>>>(
      W1hb, W2b, W3b, Woutb, Wc3, xbf,
      b1, b2, b3, bout, bcb3, w1t, ts,
      wbuf, z1buf, z2buf, cnts, (float*)d_out);
}

// Round 5
// 3357.521 us; speedup vs baseline: 1.4015x; 1.4015x over previous
//
#include <hip/hip_runtime.h>
#include <hip/hip_bf16.h>
#include <stdint.h>

// RecognitionODEGRU R11 — hardware TLP: 32 half-chains, 2 blocks per CU.
// R10 proved waits are NOT the bottleneck (software A/B interleave = exactly
// 2x R7): per-phase cost is intrinsic latency (MALL stage, L2 weight loads,
// counter RTs) exposed at 4 waves/CU. R11 halves each chain (16 rows, M=16)
// -> 512 blocks, 2 co-resident per CU; the wave scheduler overlaps the two
// blocks' stalls. Same nb on both co-resident blocks (i, i+256) keeps weight
// L1/L2 reuse; XCD = nb%8 layout preserved. Protocol/counters = R7 verbatim
// (16 producers/chain, +16 targets). Waves: z-phases 4x16 cols; k/gates
// waves 0,1 own the 32 cols + h-state; waves 2,3 stage+barrier only.
//
// Shapes: B=512, T=8, D=512, H=512, NSTEPS=4.
// d_out: outs[-1] (512,128) | h (512,512) | c=zeros (512,512), f32.

#define B_ 512
#define T_ 8
#define H_ 512
#define D_ 512

typedef short short8 __attribute__((ext_vector_type(8)));
typedef float f32x4 __attribute__((ext_vector_type(4)));
typedef __hip_bfloat16 bf16;
typedef unsigned long long u64;

__device__ __forceinline__ float sigm(float x){ return 1.f/(1.f+__expf(-x)); }

#define MFMA16(a,b,c) __builtin_amdgcn_mfma_f32_16x16x32_bf16((a),(b),(c),0,0,0)
#define ALD4(p)   __hip_atomic_load((p), __ATOMIC_RELAXED, __HIP_MEMORY_SCOPE_AGENT)
#define AST8(p,v) __hip_atomic_store((u64*)(p),(v),__ATOMIC_RELAXED,__HIP_MEMORY_SCOPE_AGENT)

__device__ __forceinline__ void wait_ge(unsigned* c, unsigned tgt, int* dead){
  if (threadIdx.x == 0){
    if (!*dead){
      int it = 0;
      while (ALD4(c) < tgt){
        __builtin_amdgcn_s_sleep(1);
        if (++it > 50000000){ *dead = 1; break; }  // terminate visibly, no hang
      }
    }
  }
  __syncthreads();
}
__device__ __forceinline__ void publish(unsigned* c){
  __builtin_amdgcn_s_waitcnt(0);   // each wave drains its stores before barrier
  __syncthreads();
  if (threadIdx.x == 0)
    __hip_atomic_fetch_add(c, 1u, __ATOMIC_RELAXED, __HIP_MEMORY_SCOPE_AGENT);
}

// Coherent slab stage: CH 16B-chunks/thread, 2^SH chunks per row (MALL path).
template<int CH, int SH>
__device__ __forceinline__ void stageC16(bf16* lds, int lstr, const bf16* g, int gstr){
  f32x4 tmp[CH];
#pragma unroll
  for (int j = 0; j < CH; ++j){
    int idx = j*256 + threadIdx.x;
    const bf16* p = g + (size_t)(idx >> SH)*gstr + (size_t)(idx & ((1<<SH)-1))*8;
    asm volatile("global_load_dwordx4 %0, %1, off sc0 sc1" : "=v"(tmp[j]) : "v"(p));
  }
  asm volatile("s_waitcnt vmcnt(0)" ::: "memory");
  __builtin_amdgcn_sched_barrier(0);   // keep ds_writes below the waitcnt
#pragma unroll
  for (int j = 0; j < CH; ++j){
    int idx = j*256 + threadIdx.x;
    *(f32x4*)&lds[(idx >> SH)*lstr + (idx & ((1<<SH)-1))*8] = tmp[j];
  }
}
// Plain (L2-cached) slab stage: CH 16B-chunks/thread, 2^SH chunks per row.
template<int CH, int SH>
__device__ __forceinline__ void stageP(bf16* lds, int lstr, const bf16* g, size_t gstr){
#pragma unroll
  for (int j = 0; j < CH; ++j){
    int idx = j*256 + threadIdx.x;
    *(short8*)&lds[(idx >> SH)*lstr + (idx & ((1<<SH)-1))*8] =
        *(const short8*)(g + (size_t)(idx >> SH)*gstr + (size_t)(idx & ((1<<SH)-1))*8);
  }
}

__device__ __forceinline__ u64 pk4(float a0, float a1, float a2, float a3){
  union { bf16 h[4]; u64 q; } u;
  u.h[0] = __float2bfloat16(a0); u.h[1] = __float2bfloat16(a1);
  u.h[2] = __float2bfloat16(a2); u.h[3] = __float2bfloat16(a3);
  return u.q;
}

// LDS: slab 16x1032 @0 (33024B) | t0s/dts/tcs [16 each] @33024 (192B)
//      dead @33216   -> total 33220, request 33280
__global__ __launch_bounds__(256, 2) void persist_k(
    const bf16* __restrict__ W1hb, const bf16* __restrict__ W2b,
    const bf16* __restrict__ W3b,  const bf16* __restrict__ Woutb,
    const bf16* __restrict__ Wc3,  const bf16* __restrict__ xbf,
    const float* __restrict__ b1,  const float* __restrict__ b2,
    const float* __restrict__ b3,  const float* __restrict__ bout,
    const float* __restrict__ bcb3,const float* __restrict__ w1t,
    const float* __restrict__ ts,
    bf16* wbuf, bf16* z1buf, bf16* z2buf,
    unsigned* cnts, float* dout)
{
  extern __shared__ char smem[];
  bf16* slab = (bf16*)smem;
  float* t0s = (float*)(smem + 33024);
  float* dts = t0s + 16;
  float* tcs = dts + 16;
  int* dead  = (int*)(smem + 33216);

  const int tid = threadIdx.x, lane = tid & 63, wv = tid >> 6;
  const int fr = lane & 15, quad = lane >> 4;
  const int nb = blockIdx.x & 15;     // weight slice — XCD = nb%8 (L2 residency)
  const int ch = blockIdx.x >> 4;     // 32 half-chains (16 rows each)
  const int gm0 = ch * 16;

  unsigned* cz1 = cnts + ch*128;
  unsigned* cz2 = cz1 + 32;
  unsigned* cw  = cz1 + 64;
  unsigned* cgt = cz1 + 96;

  if (tid < 16){
    float t0 = ts[(gm0 + tid)*T_];
    t0s[tid] = t0; tcs[tid] = t0; dts[tid] = 0.f;
  }
  if (tid == 0) *dead = 0;
  __syncthreads();

  // per-lane constant vectors (4 consecutive output cols: quad*4 + j)
  const int zc0 = 64*nb + 16*wv + quad*4;          // z-phase cols (wave-split N)
  const int kc0 = 32*nb + 16*(wv & 1) + quad*4;    // k/gates/h cols (waves 0,1)
  const f32x4 b1v  = *(const f32x4*)&b1[zc0];
  const f32x4 w1tv = *(const f32x4*)&w1t[zc0];
  const f32x4 b2v  = *(const f32x4*)&b2[zc0];
  const f32x4 b3v  = *(const f32x4*)&b3[kc0];
  f32x4 bcv[4];
#pragma unroll
  for (int g = 0; g < 4; ++g)
    bcv[g] = *(const f32x4*)&bcb3[nb*128 + g*32 + 16*(wv & 1) + quad*4];
  const f32x4 bov = *(const f32x4*)&bout[16*(nb & 7) + quad*4];

  // weight row pointers (A-operand fragments)
  const bf16* w1p = W1hb  + (size_t)(64*nb + 16*wv + fr)*512  + quad*8;
  const bf16* w2p = W2b   + (size_t)(64*nb + 16*wv + fr)*1024 + quad*8;
  const bf16* w3p = W3b   + (size_t)(32*nb + 16*(wv & 1) + fr)*1024 + quad*8;
  const bf16* wop = Woutb + (size_t)(16*(nb & 7) + fr)*512 + quad*8;
  const bf16* wcp[4];
#pragma unroll
  for (int g = 0; g < 4; ++g)
    wcp[g] = Wc3 + (size_t)(nb*128 + g*32 + 16*(wv & 1) + fr)*1024 + quad*8;

  float hreg[4] = {0,0,0,0}, kacc[4] = {0,0,0,0};   // live in waves 0,1 only
  unsigned tz1 = 16, tz2 = 16, tw = 16, tg = 16;

  for (int s = 0; s < T_; ++s){
    for (int sub = 0; sub < 4; ++sub){
      for (int e = 1; e <= 4; ++e){
        // ===== z1 = swish(w @ W1^T + t*w1t + b1), M16 N64 K512 =====
        wait_ge(cw, tw, dead);
        stageC16<4,6>(slab, 520, wbuf + (size_t)gm0*512, 512);
        __syncthreads();
        {
          f32x4 a0 = {0,0,0,0};
#pragma unroll 4
          for (int k = 0; k < 16; ++k){
            short8 wt = *(const short8*)(w1p + k*32);
            a0 = MFMA16(wt, *(const short8*)&slab[fr*520 + k*32 + quad*8], a0);
          }
          float t0v = tcs[fr];
          float s0[4];
#pragma unroll
          for (int j = 0; j < 4; ++j){
            float v0 = a0[j] + b1v[j] + t0v*w1tv[j];
            s0[j] = v0*sigm(v0);
          }
          AST8(z1buf + (size_t)(gm0 + fr)*1024 + zc0, pk4(s0[0],s0[1],s0[2],s0[3]));
          publish(cz1);
        }
        // ===== z2 = swish(z1 @ W2^T + b2), M16 N64 K1024 =====
        wait_ge(cz1, tz1, dead); tz1 += 16;
        stageC16<8,7>(slab, 1032, z1buf + (size_t)gm0*1024, 1024);
        __syncthreads();
        {
          f32x4 a0 = {0,0,0,0};
#pragma unroll 4
          for (int k = 0; k < 32; ++k){
            short8 wt = *(const short8*)(w2p + k*32);
            a0 = MFMA16(wt, *(const short8*)&slab[fr*1032 + k*32 + quad*8], a0);
          }
          float s0[4];
#pragma unroll
          for (int j = 0; j < 4; ++j){
            float v0 = a0[j] + b2v[j];
            s0[j] = v0*sigm(v0);
          }
          AST8(z2buf + (size_t)(gm0 + fr)*1024 + zc0, pk4(s0[0],s0[1],s0[2],s0[3]));
          publish(cz2);
        }
        // ===== k = z2 @ W3^T + b3 ; RK4 in registers, M16 N32 K1024 =====
        wait_ge(cz2, tz2, dead); tz2 += 16;
        stageC16<8,7>(slab, 1032, z2buf + (size_t)gm0*1024, 1024);
        __syncthreads();
        if (wv < 2){
          f32x4 ak = {0,0,0,0};
#pragma unroll 8
          for (int k = 0; k < 32; ++k){
            ak = MFMA16(*(const short8*)(w3p + k*32),
                        *(const short8*)&slab[fr*1032 + k*32 + quad*8], ak);
          }
          const float dtv = dts[fr];
          float w4[4];
#pragma unroll
          for (int j = 0; j < 4; ++j){
            float v = ak[j] + b3v[j];
            float ka = (e == 1) ? v : kacc[j] + ((e == 4) ? 1.f : 2.f)*v;
            if (e < 4){ kacc[j] = ka; w4[j] = hreg[j] + ((e == 3) ? 1.f : 0.5f)*dtv*v; }
            else      { hreg[j] = hreg[j] + dtv*(1.f/6.f)*ka; w4[j] = hreg[j]; }
          }
          AST8(wbuf + (size_t)(gm0 + fr)*512 + kc0, pk4(w4[0],w4[1],w4[2],w4[3]));
        }
        if (tid < 16){
          float ce = (e <= 2) ? ((float)sub + 0.5f) : ((float)sub + 1.f);
          tcs[tid] = t0s[tid] + dts[tid]*ce;
        }
        publish(cw); tw += 16;
      }
    }
    // ===== gates: [w|x_s] @ Wc3^T (4 groups r|z|hn|in x 32 cols), K=1024 =====
    wait_ge(cw, tw, dead);
    stageC16<4,6>(slab, 1032, wbuf + (size_t)gm0*512, 512);
    stageP<4,6>(slab + 512, 1032, xbf + ((size_t)gm0*T_ + s)*512, (size_t)T_*512);
    __syncthreads();
    publish(cgt);   // old w consumed (staged); safe to overwrite after all 16 publish
    {
      f32x4 ag[4] = {{0,0,0,0},{0,0,0,0},{0,0,0,0},{0,0,0,0}};
      if (wv < 2){
#pragma unroll 4
        for (int k = 0; k < 32; ++k){
          short8 xv = *(const short8*)&slab[fr*1032 + k*32 + quad*8];
#pragma unroll
          for (int g = 0; g < 4; ++g)
            ag[g] = MFMA16(*(const short8*)(wcp[g] + k*32), xv, ag[g]);
        }
      }
      wait_ge(cgt, tg, dead); tg += 16;
      if (wv < 2){
#pragma unroll
        for (int j = 0; j < 4; ++j){
          float r_ = sigm(ag[0][j] + bcv[0][j]);
          float z_ = sigm(ag[1][j] + bcv[1][j]);
          float hn = ag[2][j] + bcv[2][j];
          float in = ag[3][j] + bcv[3][j];
          float n_ = tanhf(in + r_*hn);
          hreg[j] = (1.f - z_)*n_ + z_*hreg[j];
        }
        AST8(wbuf + (size_t)(gm0 + fr)*512 + kc0, pk4(hreg[0],hreg[1],hreg[2],hreg[3]));
      }
      if (tid < 16){
        float t0n = ts[(gm0 + tid)*T_ + s];
        float t1  = (s < T_-1) ? ts[(gm0 + tid)*T_ + s + 1] : t0n;
        t0s[tid] = t0n; tcs[tid] = t0n; dts[tid] = (t1 - t0n)*0.25f;
      }
      publish(cw); tw += 16;
    }
  }
  // ===== final: out = h @ Wout^T + bout ; h ; c = 0 =====
  wait_ge(cw, tw, dead);
  stageC16<4,6>(slab, 520, wbuf + (size_t)gm0*512, 512);
  __syncthreads();
  if (nb < 8 && wv == 0){   // 8 n-blocks x 16 cols cover the 128 outs
    f32x4 ao = {0,0,0,0};
#pragma unroll 4
    for (int k = 0; k < 16; ++k){
      ao = MFMA16(*(const short8*)(wop + k*32),
                  *(const short8*)&slab[fr*520 + k*32 + quad*8], ao);
    }
    f32x4 o;
#pragma unroll
    for (int j = 0; j < 4; ++j) o[j] = ao[j] + bov[j];
    *(f32x4*)&dout[(size_t)(gm0 + fr)*128 + 16*nb + quad*4] = o;
  }
  if (wv < 2){
    f32x4 hv; hv[0]=hreg[0]; hv[1]=hreg[1]; hv[2]=hreg[2]; hv[3]=hreg[3];
    *(f32x4*)&dout[(size_t)B_*128 + (size_t)(gm0 + fr)*512 + kc0] = hv;
    f32x4 z4 = {0,0,0,0};
    *(f32x4*)&dout[(size_t)B_*128 + (size_t)B_*512 + (size_t)(gm0 + fr)*512 + kc0] = z4;
  }
}

// ---- prolog kernels ----
__global__ void conv_k(const float* __restrict__ in, bf16* __restrict__ out,
                       int rows, int kin, int kout)
{
  int idx = blockIdx.x*256 + threadIdx.x;
  if (idx >= rows*kout) return;
  int r = idx / kout, k = idx - r*kout;
  out[idx] = __float2bfloat16(k < kin ? in[(size_t)r*kin + k] : 0.f);
}

__global__ void w1t_k(const float* __restrict__ W1, float* __restrict__ w1t)
{
  int i = blockIdx.x*256 + threadIdx.x;
  if (i < 1024) w1t[i] = W1[(size_t)i*513 + 512];
}

// Wc3 row R = n16*128 + g*32 + c; hidden col hc = n16*32 + c.
// K: [0:512]=h-part, [512:1024]=x-part. g=0:r g=1:z g=2:hn=[Whh_n|0] g=3:in=[0|Wih_n].
__global__ void wc3_k(const float* __restrict__ Wih, const float* __restrict__ Whh,
                      const float* __restrict__ bih, const float* __restrict__ bhh,
                      bf16* __restrict__ Wc3, float* __restrict__ bcb3)
{
  int idx = blockIdx.x*256 + threadIdx.x;
  if (idx >= 2048*1024) return;
  int R = idx >> 10, k = idx & 1023;
  int n16 = R >> 7, g = (R >> 5) & 3, c = R & 31;
  int hc = n16*32 + c;
  float v;
  if      (g == 0) v = (k < 512) ? Whh[(size_t)hc*512 + k]        : Wih[(size_t)hc*512 + k - 512];
  else if (g == 1) v = (k < 512) ? Whh[(size_t)(512+hc)*512 + k]  : Wih[(size_t)(512+hc)*512 + k - 512];
  else if (g == 2) v = (k < 512) ? Whh[(size_t)(1024+hc)*512 + k] : 0.f;
  else             v = (k < 512) ? 0.f                             : Wih[(size_t)(1024+hc)*512 + k - 512];
  Wc3[idx] = __float2bfloat16(v);
  if (k == 0){
    if      (g == 0) bcb3[R] = bih[hc] + bhh[hc];
    else if (g == 1) bcb3[R] = bih[512 + hc] + bhh[512 + hc];
    else if (g == 2) bcb3[R] = bhh[1024 + hc];
    else             bcb3[R] = bih[1024 + hc];
  }
}

__global__ void init_k(bf16* __restrict__ wbuf, unsigned* __restrict__ cnts)
{
  int idx = blockIdx.x*256 + threadIdx.x;
  if (idx < B_*H_) wbuf[idx] = __float2bfloat16(0.f);
  if (idx < 32*128){
    int off = idx & 127;
    cnts[idx] = (off == 64) ? 16u : 0u;   // cw pre-armed (initial w=0 published)
  }
}

extern "C" void kernel_launch(void* const* d_in, const int* in_sizes, int n_in,
                              void* d_out, int out_size, void* d_ws, size_t ws_size,
                              hipStream_t stream)
{
  const float* x    = (const float*)d_in[0];
  const float* ts   = (const float*)d_in[1];
  const float* Wih  = (const float*)d_in[2];
  const float* Whh  = (const float*)d_in[3];
  const float* bih  = (const float*)d_in[4];
  const float* bhh  = (const float*)d_in[5];
  const float* Wout = (const float*)d_in[6];
  const float* bout = (const float*)d_in[7];
  const float* W1   = (const float*)d_in[8];
  const float* b1   = (const float*)d_in[9];
  const float* W2   = (const float*)d_in[10];
  const float* b2   = (const float*)d_in[11];
  const float* W3   = (const float*)d_in[12];
  const float* b3   = (const float*)d_in[13];

  char* ws = (char*)d_ws;
  size_t off = 0;
  auto alloc = [&](size_t n){ void* p = ws + off; off += (n + 255) & ~(size_t)255; return p; };

  bf16* xbf   = (bf16*)alloc((size_t)B_*T_*D_*2);
  bf16* W1hb  = (bf16*)alloc((size_t)1024*512*2);
  bf16* W2b   = (bf16*)alloc((size_t)1024*1024*2);
  bf16* W3b   = (bf16*)alloc((size_t)512*1024*2);
  bf16* Woutb = (bf16*)alloc((size_t)128*512*2);
  bf16* Wc3   = (bf16*)alloc((size_t)2048*1024*2);
  float* bcb3 = (float*)alloc((size_t)2048*4);
  float* w1t  = (float*)alloc((size_t)1024*4);
  bf16* wbuf  = (bf16*)alloc((size_t)B_*H_*2);
  bf16* z1buf = (bf16*)alloc((size_t)B_*1024*2);
  bf16* z2buf = (bf16*)alloc((size_t)B_*1024*2);
  unsigned* cnts = (unsigned*)alloc((size_t)32*128*4);

  auto conv = [&](const float* in, bf16* out, int rows, int kin, int kout){
    int n = rows*kout;
    conv_k<<<(n + 255)/256, 256, 0, stream>>>(in, out, rows, kin, kout);
  };
  conv(x, xbf, B_*T_, D_, D_);
  conv(W1, W1hb, 1024, 513, 512);   // col 512 handled via w1t rank-1 term
  conv(W2, W2b, 1024, 1024, 1024);
  conv(W3, W3b, 512, 1024, 1024);
  conv(Wout, Woutb, 128, 512, 512);
  w1t_k<<<4, 256, 0, stream>>>(W1, w1t);
  wc3_k<<<(2048*1024)/256, 256, 0, stream>>>(Wih, Whh, bih, bhh, Wc3, bcb3);
  init_k<<<(B_*H_ + 255)/256, 256, 0, stream>>>(wbuf, cnts);

  (void)hipFuncSetAttribute((const void*)persist_k,
                            hipFuncAttributeMaxDynamicSharedMemorySize, 33280);
  persist_k<<<512, 256, 33280, stream>>>(
      W1hb, W2b, W3b, Woutb, Wc3, xbf,
      b1, b2, b3, bout, bcb3, w1t, ts,
      wbuf, z1buf, z2buf, cnts, (float*)d_out);
}

// Round 6
// 1902.579 us; speedup vs baseline: 2.4732x; 1.7647x over previous
//
#include <hip/hip_runtime.h>
#include <hip/hip_bf16.h>
#include <stdint.h>

// RecognitionODEGRU R12 — R7 + register-resident W1/W2 fragments.
// R9/R10/R11 falsified every restructure (XCD-local coherence, software
// interleave, hardware TLP): R7's topology is the optimum; per-phase cost is
// fabric (MALL) handshake+stage plus in-block compute. R12 removes the
// compute section's L2 weight traffic: W1 (64 VGPR) and W2 (128 VGPR)
// A-fragments are loop-invariant across all 393 phases -> hoisted to
// registers once (LDS 132KB forces 1 block/CU = 1 wave/SIMD, so VGPR budget
// is 512: free). z1/z2 K-loops fully unrolled for static array indexing.
// Everything else (protocol, staging, counters, layout) R7-verbatim.
//
// Shapes: B=512, T=8, D=512, H=512, NSTEPS=4.
// d_out: outs[-1] (512,128) | h (512,512) | c=zeros (512,512), f32.

#define B_ 512
#define T_ 8
#define H_ 512
#define D_ 512

typedef short short8 __attribute__((ext_vector_type(8)));
typedef float f32x4 __attribute__((ext_vector_type(4)));
typedef __hip_bfloat16 bf16;
typedef unsigned long long u64;

__device__ __forceinline__ float sigm(float x){ return 1.f/(1.f+__expf(-x)); }

#define MFMA16(a,b,c) __builtin_amdgcn_mfma_f32_16x16x32_bf16((a),(b),(c),0,0,0)
#define ALD4(p)   __hip_atomic_load((p), __ATOMIC_RELAXED, __HIP_MEMORY_SCOPE_AGENT)
#define AST8(p,v) __hip_atomic_store((u64*)(p),(v),__ATOMIC_RELAXED,__HIP_MEMORY_SCOPE_AGENT)

__device__ __forceinline__ void wait_ge(unsigned* c, unsigned tgt, int* dead){
  if (threadIdx.x == 0){
    if (!*dead){
      int it = 0;
      while (ALD4(c) < tgt){
        __builtin_amdgcn_s_sleep(1);
        if (++it > 50000000){ *dead = 1; break; }  // terminate visibly, no hang
      }
    }
  }
  __syncthreads();
}
__device__ __forceinline__ void publish(unsigned* c){
  __builtin_amdgcn_s_waitcnt(0);   // each wave drains its stores before barrier
  __syncthreads();
  if (threadIdx.x == 0)
    __hip_atomic_fetch_add(c, 1u, __ATOMIC_RELAXED, __HIP_MEMORY_SCOPE_AGENT);
}

// Coherent slab stage: CH 16B-chunks/thread, 2^SH chunks per row (MALL path).
template<int CH, int SH>
__device__ __forceinline__ void stageC16(bf16* lds, int lstr, const bf16* g, int gstr){
  f32x4 tmp[CH];
#pragma unroll
  for (int j = 0; j < CH; ++j){
    int idx = j*256 + threadIdx.x;
    const bf16* p = g + (size_t)(idx >> SH)*gstr + (size_t)(idx & ((1<<SH)-1))*8;
    asm volatile("global_load_dwordx4 %0, %1, off sc0 sc1" : "=v"(tmp[j]) : "v"(p));
  }
  asm volatile("s_waitcnt vmcnt(0)" ::: "memory");
  __builtin_amdgcn_sched_barrier(0);   // keep ds_writes below the waitcnt
#pragma unroll
  for (int j = 0; j < CH; ++j){
    int idx = j*256 + threadIdx.x;
    *(f32x4*)&lds[(idx >> SH)*lstr + (idx & ((1<<SH)-1))*8] = tmp[j];
  }
}
// Plain (L2-cached) slab stage: CH 16B-chunks/thread, 2^SH chunks per row.
template<int CH, int SH>
__device__ __forceinline__ void stageP(bf16* lds, int lstr, const bf16* g, size_t gstr){
#pragma unroll
  for (int j = 0; j < CH; ++j){
    int idx = j*256 + threadIdx.x;
    *(short8*)&lds[(idx >> SH)*lstr + (idx & ((1<<SH)-1))*8] =
        *(const short8*)(g + (size_t)(idx >> SH)*gstr + (size_t)(idx & ((1<<SH)-1))*8);
  }
}

__device__ __forceinline__ u64 pk4(float a0, float a1, float a2, float a3){
  union { bf16 h[4]; u64 q; } u;
  u.h[0] = __float2bfloat16(a0); u.h[1] = __float2bfloat16(a1);
  u.h[2] = __float2bfloat16(a2); u.h[3] = __float2bfloat16(a3);
  return u.q;
}

// LDS: slab 32x1032 @0 (66048B) | W3s 32x1032 @66048 (66048B, persistent)
//      t0s/dts/tcs @132096 | dead @132480
__global__ __launch_bounds__(256, 1) void persist_k(
    const bf16* __restrict__ W1hb, const bf16* __restrict__ W2b,
    const bf16* __restrict__ W3b,  const bf16* __restrict__ Woutb,
    const bf16* __restrict__ Wc3,  const bf16* __restrict__ xbf,
    const float* __restrict__ b1,  const float* __restrict__ b2,
    const float* __restrict__ b3,  const float* __restrict__ bout,
    const float* __restrict__ bcb3,const float* __restrict__ w1t,
    const float* __restrict__ ts,
    bf16* wbuf, bf16* z1buf, bf16* z2buf,
    unsigned* cnts, float* dout)
{
  extern __shared__ char smem[];
  bf16* slab = (bf16*)smem;
  bf16* W3s  = (bf16*)(smem + 66048);
  float* t0s = (float*)(smem + 132096);
  float* dts = t0s + 32;
  float* tcs = dts + 32;
  int* dead  = (int*)(smem + 132480);

  const int tid = threadIdx.x, lane = tid & 63, wv = tid >> 6;
  const int fr = lane & 15, quad = lane >> 4;
  const int nb = blockIdx.x & 15;
  const int mb = blockIdx.x >> 4;     // 16 chains
  const int gm0 = mb * 32;
  const int wm = wv & 1;              // batch half (k/gates/final-h)
  const int wn = wv >> 1;             // 16-col half (k/gates/final-h)

  unsigned* cz1 = cnts + mb*128;
  unsigned* cz2 = cz1 + 32;
  unsigned* cw  = cz1 + 64;
  unsigned* cgt = cz1 + 96;

  // W3 slice -> LDS once (32 k-cols of this block, K=1024)
  stageP<16,7>(W3s, 1032, W3b + (size_t)(32*nb)*1024, 1024);
  if (tid < 32){
    float t0 = ts[(gm0 + tid)*T_];
    t0s[tid] = t0; tcs[tid] = t0; dts[tid] = 0.f;
  }
  if (tid == 0) *dead = 0;
  __syncthreads();

  // per-lane constant vectors (4 consecutive output cols: quad*4 + j)
  const int zc0 = 64*nb + 16*wv + quad*4;   // z-phase col base (per-wave N-slice)
  const int kc0 = 32*nb + 16*wn + quad*4;   // k/gates/final-h col base
  const f32x4 b1v  = *(const f32x4*)&b1[zc0];
  const f32x4 w1tv = *(const f32x4*)&w1t[zc0];
  const f32x4 b2v  = *(const f32x4*)&b2[zc0];
  const f32x4 b3v  = *(const f32x4*)&b3[kc0];
  f32x4 bcv[4];
#pragma unroll
  for (int g = 0; g < 4; ++g)
    bcv[g] = *(const f32x4*)&bcb3[nb*128 + g*32 + 16*wn + quad*4];
  const f32x4 bov = *(const f32x4*)&bout[16*(nb & 7) + quad*4];

  // weight row pointers (A-operand fragments; one row-set per wave in z phases)
  const bf16* w1p = W1hb  + (size_t)(64*nb + 16*wv + fr)*512  + quad*8;
  const bf16* w2p = W2b   + (size_t)(64*nb + 16*wv + fr)*1024 + quad*8;
  const bf16* wop = Woutb + (size_t)(16*(nb & 7) + fr)*512 + quad*8;
  const bf16* wcp[4];
#pragma unroll
  for (int g = 0; g < 4; ++g)
    wcp[g] = Wc3 + (size_t)(nb*128 + g*32 + 16*wn + fr)*1024 + quad*8;

  // ===== register-resident weight fragments (loop-invariant, 192 VGPR) =====
  short8 w1f[16], w2f[32];
#pragma unroll
  for (int k = 0; k < 16; ++k) w1f[k] = *(const short8*)(w1p + k*32);
#pragma unroll
  for (int k = 0; k < 32; ++k) w2f[k] = *(const short8*)(w2p + k*32);

  float hreg[4] = {0,0,0,0}, kacc[4] = {0,0,0,0};
  unsigned tz1 = 16, tz2 = 16, tw = 16, tg = 16;

  for (int s = 0; s < T_; ++s){
    for (int sub = 0; sub < 4; ++sub){
      for (int e = 1; e <= 4; ++e){
        // ===== z1 = swish(w @ W1^T + t*w1t + b1), M32 N64 K512 =====
        wait_ge(cw, tw, dead);
        stageC16<8,6>(slab, 520, wbuf + (size_t)gm0*512, 512);
        __syncthreads();
        {
          f32x4 a0 = {0,0,0,0}, a1 = {0,0,0,0};
#pragma unroll
          for (int k = 0; k < 16; ++k){   // full unroll: w1f[k] static (regs)
            a0 = MFMA16(w1f[k], *(const short8*)&slab[fr*520      + k*32 + quad*8], a0);
            a1 = MFMA16(w1f[k], *(const short8*)&slab[(16+fr)*520 + k*32 + quad*8], a1);
          }
          float t0v = tcs[fr], t1v = tcs[16 + fr];
          float s0[4], s1[4];
#pragma unroll
          for (int j = 0; j < 4; ++j){
            float v0 = a0[j] + b1v[j] + t0v*w1tv[j];
            float v1 = a1[j] + b1v[j] + t1v*w1tv[j];
            s0[j] = v0*sigm(v0); s1[j] = v1*sigm(v1);
          }
          AST8(z1buf + (size_t)(gm0 + fr)*1024 + zc0,      pk4(s0[0],s0[1],s0[2],s0[3]));
          AST8(z1buf + (size_t)(gm0 + 16 + fr)*1024 + zc0, pk4(s1[0],s1[1],s1[2],s1[3]));
          publish(cz1);
        }
        // ===== z2 = swish(z1 @ W2^T + b2), M32 N64 K1024 =====
        wait_ge(cz1, tz1, dead); tz1 += 16;
        stageC16<16,7>(slab, 1032, z1buf + (size_t)gm0*1024, 1024);
        __syncthreads();
        {
          f32x4 a0 = {0,0,0,0}, a1 = {0,0,0,0};
#pragma unroll
          for (int k = 0; k < 32; ++k){   // full unroll: w2f[k] static (regs)
            a0 = MFMA16(w2f[k], *(const short8*)&slab[fr*1032      + k*32 + quad*8], a0);
            a1 = MFMA16(w2f[k], *(const short8*)&slab[(16+fr)*1032 + k*32 + quad*8], a1);
          }
          float s0[4], s1[4];
#pragma unroll
          for (int j = 0; j < 4; ++j){
            float v0 = a0[j] + b2v[j], v1 = a1[j] + b2v[j];
            s0[j] = v0*sigm(v0); s1[j] = v1*sigm(v1);
          }
          AST8(z2buf + (size_t)(gm0 + fr)*1024 + zc0,      pk4(s0[0],s0[1],s0[2],s0[3]));
          AST8(z2buf + (size_t)(gm0 + 16 + fr)*1024 + zc0, pk4(s1[0],s1[1],s1[2],s1[3]));
          publish(cz2);
        }
        // ===== k = z2 @ W3^T + b3 ; RK4 in registers, M32 N32 K1024 =====
        wait_ge(cz2, tz2, dead); tz2 += 16;
        stageC16<16,7>(slab, 1032, z2buf + (size_t)gm0*1024, 1024);
        __syncthreads();
        {
          f32x4 ak = {0,0,0,0};
#pragma unroll 8
          for (int k = 0; k < 32; ++k){
            ak = MFMA16(*(const short8*)&W3s[(16*wn + fr)*1032 + k*32 + quad*8],
                        *(const short8*)&slab[(wm*16 + fr)*1032 + k*32 + quad*8], ak);
          }
          const int r = wm*16 + fr;
          const float dtv = dts[r];
          float w4[4];
#pragma unroll
          for (int j = 0; j < 4; ++j){
            float v = ak[j] + b3v[j];
            float ka = (e == 1) ? v : kacc[j] + ((e == 4) ? 1.f : 2.f)*v;
            if (e < 4){ kacc[j] = ka; w4[j] = hreg[j] + ((e == 3) ? 1.f : 0.5f)*dtv*v; }
            else      { hreg[j] = hreg[j] + dtv*(1.f/6.f)*ka; w4[j] = hreg[j]; }
          }
          AST8(wbuf + (size_t)(gm0 + r)*512 + kc0, pk4(w4[0],w4[1],w4[2],w4[3]));
          if (tid < 32){
            float ce = (e <= 2) ? ((float)sub + 0.5f) : ((float)sub + 1.f);
            tcs[tid] = t0s[tid] + dts[tid]*ce;
          }
          publish(cw); tw += 16;
        }
      }
    }
    // ===== gates: [w|x_s] @ Wc3^T (4 groups r|z|hn|in x 32 cols), K=1024 =====
    wait_ge(cw, tw, dead);
    stageC16<8,6>(slab, 1032, wbuf + (size_t)gm0*512, 512);
    stageP<8,6>(slab + 512, 1032, xbf + ((size_t)gm0*T_ + s)*512, (size_t)T_*512);
    __syncthreads();
    publish(cgt);   // old w consumed (staged); safe to overwrite after all 16 publish
    {
      f32x4 ag[4] = {{0,0,0,0},{0,0,0,0},{0,0,0,0},{0,0,0,0}};
#pragma unroll 4
      for (int k = 0; k < 32; ++k){
        short8 xv = *(const short8*)&slab[(wm*16 + fr)*1032 + k*32 + quad*8];
#pragma unroll
        for (int g = 0; g < 4; ++g)
          ag[g] = MFMA16(*(const short8*)(wcp[g] + k*32), xv, ag[g]);
      }
      wait_ge(cgt, tg, dead); tg += 16;
      const int r = wm*16 + fr;
#pragma unroll
      for (int j = 0; j < 4; ++j){
        float r_ = sigm(ag[0][j] + bcv[0][j]);
        float z_ = sigm(ag[1][j] + bcv[1][j]);
        float hn = ag[2][j] + bcv[2][j];
        float in = ag[3][j] + bcv[3][j];
        float n_ = tanhf(in + r_*hn);
        hreg[j] = (1.f - z_)*n_ + z_*hreg[j];
      }
      AST8(wbuf + (size_t)(gm0 + r)*512 + kc0, pk4(hreg[0],hreg[1],hreg[2],hreg[3]));
      if (tid < 32){
        float t0n = ts[(gm0 + tid)*T_ + s];
        float t1  = (s < T_-1) ? ts[(gm0 + tid)*T_ + s + 1] : t0n;
        t0s[tid] = t0n; tcs[tid] = t0n; dts[tid] = (t1 - t0n)*0.25f;
      }
      publish(cw); tw += 16;
    }
  }
  // ===== final: out = h @ Wout^T + bout ; h ; c = 0 =====
  wait_ge(cw, tw, dead);
  stageC16<8,6>(slab, 520, wbuf + (size_t)gm0*512, 512);
  __syncthreads();
  if (nb < 8 && wv < 2){   // 8 n-blocks x 16 cols cover the 128 outs; wv = batch half
    f32x4 ao = {0,0,0,0};
#pragma unroll 4
    for (int k = 0; k < 16; ++k){
      ao = MFMA16(*(const short8*)(wop + k*32),
                  *(const short8*)&slab[(wv*16 + fr)*520 + k*32 + quad*8], ao);
    }
    f32x4 o;
#pragma unroll
    for (int j = 0; j < 4; ++j) o[j] = ao[j] + bov[j];
    *(f32x4*)&dout[(size_t)(gm0 + wv*16 + fr)*128 + 16*nb + quad*4] = o;
  }
  {
    const int r = wm*16 + fr;
    f32x4 hv; hv[0]=hreg[0]; hv[1]=hreg[1]; hv[2]=hreg[2]; hv[3]=hreg[3];
    *(f32x4*)&dout[(size_t)B_*128 + (size_t)(gm0 + r)*512 + kc0] = hv;
    f32x4 z4 = {0,0,0,0};
    *(f32x4*)&dout[(size_t)B_*128 + (size_t)B_*512 + (size_t)(gm0 + r)*512 + kc0] = z4;
  }
}

// ---- prolog kernels ----
__global__ void conv_k(const float* __restrict__ in, bf16* __restrict__ out,
                       int rows, int kin, int kout)
{
  int idx = blockIdx.x*256 + threadIdx.x;
  if (idx >= rows*kout) return;
  int r = idx / kout, k = idx - r*kout;
  out[idx] = __float2bfloat16(k < kin ? in[(size_t)r*kin + k] : 0.f);
}

__global__ void w1t_k(const float* __restrict__ W1, float* __restrict__ w1t)
{
  int i = blockIdx.x*256 + threadIdx.x;
  if (i < 1024) w1t[i] = W1[(size_t)i*513 + 512];
}

// Wc3 row R = n16*128 + g*32 + c; hidden col hc = n16*32 + c.
// K: [0:512]=h-part, [512:1024]=x-part. g=0:r g=1:z g=2:hn=[Whh_n|0] g=3:in=[0|Wih_n].
__global__ void wc3_k(const float* __restrict__ Wih, const float* __restrict__ Whh,
                      const float* __restrict__ bih, const float* __restrict__ bhh,
                      bf16* __restrict__ Wc3, float* __restrict__ bcb3)
{
  int idx = blockIdx.x*256 + threadIdx.x;
  if (idx >= 2048*1024) return;
  int R = idx >> 10, k = idx & 1023;
  int n16 = R >> 7, g = (R >> 5) & 3, c = R & 31;
  int hc = n16*32 + c;
  float v;
  if      (g == 0) v = (k < 512) ? Whh[(size_t)hc*512 + k]        : Wih[(size_t)hc*512 + k - 512];
  else if (g == 1) v = (k < 512) ? Whh[(size_t)(512+hc)*512 + k]  : Wih[(size_t)(512+hc)*512 + k - 512];
  else if (g == 2) v = (k < 512) ? Whh[(size_t)(1024+hc)*512 + k] : 0.f;
  else             v = (k < 512) ? 0.f                             : Wih[(size_t)(1024+hc)*512 + k - 512];
  Wc3[idx] = __float2bfloat16(v);
  if (k == 0){
    if      (g == 0) bcb3[R] = bih[hc] + bhh[hc];
    else if (g == 1) bcb3[R] = bih[512 + hc] + bhh[512 + hc];
    else if (g == 2) bcb3[R] = bhh[1024 + hc];
    else             bcb3[R] = bih[1024 + hc];
  }
}

__global__ void init_k(bf16* __restrict__ wbuf, unsigned* __restrict__ cnts)
{
  int idx = blockIdx.x*256 + threadIdx.x;
  if (idx < B_*H_) wbuf[idx] = __float2bfloat16(0.f);
  if (idx < 16*128){
    int off = idx & 127;
    cnts[idx] = (off == 64) ? 16u : 0u;   // cw pre-armed (initial w=0 published)
  }
}

extern "C" void kernel_launch(void* const* d_in, const int* in_sizes, int n_in,
                              void* d_out, int out_size, void* d_ws, size_t ws_size,
                              hipStream_t stream)
{
  const float* x    = (const float*)d_in[0];
  const float* ts   = (const float*)d_in[1];
  const float* Wih  = (const float*)d_in[2];
  const float* Whh  = (const float*)d_in[3];
  const float* bih  = (const float*)d_in[4];
  const float* bhh  = (const float*)d_in[5];
  const float* Wout = (const float*)d_in[6];
  const float* bout = (const float*)d_in[7];
  const float* W1   = (const float*)d_in[8];
  const float* b1   = (const float*)d_in[9];
  const float* W2   = (const float*)d_in[10];
  const float* b2   = (const float*)d_in[11];
  const float* W3   = (const float*)d_in[12];
  const float* b3   = (const float*)d_in[13];

  char* ws = (char*)d_ws;
  size_t off = 0;
  auto alloc = [&](size_t n){ void* p = ws + off; off += (n + 255) & ~(size_t)255; return p; };

  bf16* xbf   = (bf16*)alloc((size_t)B_*T_*D_*2);
  bf16* W1hb  = (bf16*)alloc((size_t)1024*512*2);
  bf16* W2b   = (bf16*)alloc((size_t)1024*1024*2);
  bf16* W3b   = (bf16*)alloc((size_t)512*1024*2);
  bf16* Woutb = (bf16*)alloc((size_t)128*512*2);
  bf16* Wc3   = (bf16*)alloc((size_t)2048*1024*2);
  float* bcb3 = (float*)alloc((size_t)2048*4);
  float* w1t  = (float*)alloc((size_t)1024*4);
  bf16* wbuf  = (bf16*)alloc((size_t)B_*H_*2);
  bf16* z1buf = (bf16*)alloc((size_t)B_*1024*2);
  bf16* z2buf = (bf16*)alloc((size_t)B_*1024*2);
  unsigned* cnts = (unsigned*)alloc((size_t)16*128*4);

  auto conv = [&](const float* in, bf16* out, int rows, int kin, int kout){
    int n = rows*kout;
    conv_k<<<(n + 255)/256, 256, 0, stream>>>(in, out, rows, kin, kout);
  };
  conv(x, xbf, B_*T_, D_, D_);
  conv(W1, W1hb, 1024, 513, 512);   // col 512 handled via w1t rank-1 term
  conv(W2, W2b, 1024, 1024, 1024);
  conv(W3, W3b, 512, 1024, 1024);
  conv(Wout, Woutb, 128, 512, 512);
  w1t_k<<<4, 256, 0, stream>>>(W1, w1t);
  wc3_k<<<(2048*1024)/256, 256, 0, stream>>>(Wih, Whh, bih, bhh, Wc3, bcb3);
  init_k<<<(B_*H_ + 255)/256, 256, 0, stream>>>(wbuf, cnts);

  (void)hipFuncSetAttribute((const void*)persist_k,
                            hipFuncAttributeMaxDynamicSharedMemorySize, 132608);
  persist_k<<<256, 256, 132608, stream>>>(
      W1hb, W2b, W3b, Woutb, Wc3, xbf,
      b1, b2, b3, bout, bcb3, w1t, ts,
      wbuf, z1buf, z2buf, cnts, (float*)d_out);
}